// Round 3
// baseline (222.697 us; speedup 1.0000x reference)
//
#include <hip/hip_runtime.h>
#include <math.h>

#define CHB 8
#define C_NUM 64
#define NCELL 125
#define MAX_VOX 512     // safety allocation; analysis bound is 8*8*4=256
#define NITEMS 250      // 125 cells x 2 sample-halves

__device__ inline void acc8(const float4* __restrict__ rg4, int idx2, float w,
                            float4& A, float4& B) {
    float4 lo = rg4[idx2];
    float4 hi = rg4[idx2 + 1];
    A.x = fmaf(lo.x, w, A.x); A.y = fmaf(lo.y, w, A.y);
    A.z = fmaf(lo.z, w, A.z); A.w = fmaf(lo.w, w, A.w);
    B.x = fmaf(hi.x, w, B.x); B.y = fmaf(hi.y, w, B.y);
    B.z = fmaf(hi.z, w, B.z); B.w = fmaf(hi.w, w, B.w);
}

// LDS: reg 512*8*4 = 16 KB, partial 250*9*4 = 9 KB  -> 4+ blocks/CU
__global__ __launch_bounds__(256, 4) void pooler_kernel(
    const float* __restrict__ x0, const float* __restrict__ x1,
    const float* __restrict__ x2, const float* __restrict__ x3,
    const float* __restrict__ bbox, const int* __restrict__ bids,
    float* __restrict__ out)
{
    __shared__ float reg[MAX_VOX * CHB];   // [voxel][ch]
    __shared__ float partial[NITEMS * 9];  // [item][ch], padded stride 9

    const int blk = blockIdx.x;
    const int r   = blk >> 3;   // roi (128)
    const int cg  = blk & 7;    // channel group (8 x 8ch)
    const int tid = threadIdx.x;

    // ---- per-roi params (wave-uniform) ----
    const float b0 = bbox[r*7+0], b1 = bbox[r*7+1], b2 = bbox[r*7+2];
    const float b3 = bbox[r*7+3], b4 = bbox[r*7+4], b5 = bbox[r*7+5];
    const float b6 = bbox[r*7+6];
    const int bid  = bids[r];

    // level select: argmin |SC - sqrt(max(b3,b4))/20|, first-min wins
    const float rate = sqrtf(fmaxf(b3, b4)) / 20.0f;
    const float SC[4] = {0.25f, 0.125f, 0.0625f, 0.03125f};
    int lvl = 0;
    float best = fabsf(SC[0] - rate);
    #pragma unroll
    for (int j = 1; j < 4; ++j) {
        float d = fabsf(SC[j] - rate);
        if (d < best) { best = d; lvl = j; }
    }
    const float scale = SC[lvl];

    const float* f; int D;
    if (lvl == 0)      { f = x0; D = 64; }
    else if (lvl == 1) { f = x1; D = 32; }
    else if (lvl == 2) { f = x2; D = 16; }
    else               { f = x3; D = 8;  }
    const float Df = (float)D;

    // roi7 = [b1,b0,b2,b4,b3,b5, b6*(180/pi)]; theta = roi7[6]*(pi/180)
    const float ctr0 = b1 * scale;
    const float ctr1 = b0 * scale;
    const float ctr2 = b2 * scale;
    const float sz0  = b4 * scale;
    const float sz1  = b3 * scale;
    const float sz2  = b5 * scale;
    const float theta = (b6 * (180.0f / (float)M_PI)) * ((float)M_PI / 180.0f);
    float st, ct;
    sincosf(theta, &st, &ct);

    // tight sample-extent bounds: u in [0.05,0.95] -> g in +-0.45*sz
    const float hx = 0.451f * (fabsf(ct) * sz0 + fabsf(st) * sz1) + 0.01f;
    const float hy = 0.451f * (fabsf(st) * sz0 + fabsf(ct) * sz1) + 0.01f;
    const float hz = 0.451f * sz2 + 0.01f;
    const int x_lo = (int)fminf(fmaxf(ctr0 - hx, 0.0f), Df - 1.0f);
    const int y_lo = (int)fminf(fmaxf(ctr1 - hy, 0.0f), Df - 1.0f);
    const int z_lo = (int)fminf(fmaxf(ctr2 - hz, 0.0f), Df - 1.0f);
    const int x_hi = (int)fminf(fmaxf(ctr0 + hx, 0.0f), Df - 1.0f);
    const int y_hi = (int)fminf(fmaxf(ctr1 + hy, 0.0f), Df - 1.0f);
    const int z_hi = (int)fminf(fmaxf(ctr2 + hz, 0.0f), Df - 1.0f);

    const int nx = min(x_hi - x_lo + 2, D - x_lo);   // <= 8 by analysis
    const int ny = min(y_hi - y_lo + 2, D - y_lo);   // <= 8
    const int nz = min(z_hi - z_lo + 2, D - z_lo);   // <= 4

    // pow2 roundup (capped for LDS safety)
    int RX2 = 2; while (RX2 < nx) RX2 <<= 1; RX2 = min(RX2, 8);
    int RY2 = 2; while (RY2 < ny) RY2 <<= 1; RY2 = min(RY2, 8);
    int RZ2 = 2; while (RZ2 < nz) RZ2 <<= 1; RZ2 = min(RZ2, 8);
    const int lz  = __builtin_ctz(RZ2);
    const int ly  = __builtin_ctz(RY2);
    const int lx  = __builtin_ctz(RX2);
    const int sxs = lz + ly;            // x-stride shift
    const int lnv = lx + ly + lz;       // log2(nvox)
    const int nvox = 1 << lnv;

    // ---- phase A: stage region for 8 channels into LDS [voxel][ch] ----
    const size_t vox = (size_t)D * D * D;
    const float* fbase = f + ((size_t)bid * C_NUM + (size_t)cg * CHB) * vox;
    const int total_e = nvox * CHB;
    for (int e = tid; e < total_e; e += 256) {
        int ch = e >> lnv;
        int v  = e & (nvox - 1);
        int rz = v & (RZ2 - 1);
        int ry = (v >> lz) & (RY2 - 1);
        int rx = v >> sxs;
        int gx = min(x_lo + rx, D - 1);
        int gy = min(y_lo + ry, D - 1);
        int gz = min(z_lo + rz, D - 1);
        reg[v * CHB + ch] = fbase[(size_t)ch * vox + (size_t)(gx * D + gy) * D + gz];
    }
    __syncthreads();

    // ---- phase C: one thread = one (cell, sample-half) for all 8 channels ----
    if (tid < NITEMS) {
        const int cell  = tid >> 1;
        const int shalf = tid & 1;
        const int i0 = cell / 25;
        const int rem = cell - i0 * 25;
        const int i1 = rem / 5;
        const int i2 = rem - i1 * 5;

        float4 accA = make_float4(0.f, 0.f, 0.f, 0.f);
        float4 accB = make_float4(0.f, 0.f, 0.f, 0.f);
        const float4* rg4 = (const float4*)reg;

        #pragma unroll
        for (int s = 0; s < 4; ++s) {
            const int s0 = shalf, s1 = (s >> 1) & 1, s2 = s & 1;
            float u0 = ((float)i0 + ((float)s0 + 0.5f) * 0.5f) / 5.0f;
            float u1 = ((float)i1 + ((float)s1 + 0.5f) * 0.5f) / 5.0f;
            float u2 = ((float)i2 + ((float)s2 + 0.5f) * 0.5f) / 5.0f;
            float g0 = (u0 - 0.5f) * sz0;
            float g1 = (u1 - 0.5f) * sz1;
            float g2 = (u2 - 0.5f) * sz2;
            float px = ctr0 + (ct * g0 - st * g1);
            float py = ctr1 + (st * g0 + ct * g1);
            float pz = ctr2 + g2;
            float validf = ((px > -1.0f) && (px < Df) &&
                            (py > -1.0f) && (py < Df) &&
                            (pz > -1.0f) && (pz < Df)) ? 1.0f : 0.0f;
            float q0 = fminf(fmaxf(px, 0.0f), Df - 1.0f);
            float q1 = fminf(fmaxf(py, 0.0f), Df - 1.0f);
            float q2 = fminf(fmaxf(pz, 0.0f), Df - 1.0f);
            int A0 = (int)q0, A1 = (int)q1, A2 = (int)q2;
            float f0 = q0 - (float)A0;
            float f1 = q1 - (float)A1;
            float f2 = q2 - (float)A2;
            int d0 = ((A0 + 1 < D) ? 1 : 0) << sxs;
            int d1 = ((A1 + 1 < D) ? 1 : 0) << lz;
            int d2 = (A2 + 1 < D) ? 1 : 0;
            int base = ((A0 - x_lo) << sxs) + ((A1 - y_lo) << lz) + (A2 - z_lo);

            float wx0 = 1.0f - f0, wx1 = f0;
            float wy0 = 1.0f - f1, wy1 = f1;
            float wz0 = (1.0f - f2) * validf, wz1 = f2 * validf;
            float w00 = wx0 * wy0, w01 = wx0 * wy1;
            float w10 = wx1 * wy0, w11 = wx1 * wy1;

            acc8(rg4, (base) * 2,                w00 * wz0, accA, accB);
            acc8(rg4, (base + d2) * 2,           w00 * wz1, accA, accB);
            acc8(rg4, (base + d1) * 2,           w01 * wz0, accA, accB);
            acc8(rg4, (base + d1 + d2) * 2,      w01 * wz1, accA, accB);
            acc8(rg4, (base + d0) * 2,           w10 * wz0, accA, accB);
            acc8(rg4, (base + d0 + d2) * 2,      w10 * wz1, accA, accB);
            acc8(rg4, (base + d0 + d1) * 2,      w11 * wz0, accA, accB);
            acc8(rg4, (base + d0 + d1 + d2) * 2, w11 * wz1, accA, accB);
        }

        const int pb = tid * 9;
        partial[pb + 0] = accA.x; partial[pb + 1] = accA.y;
        partial[pb + 2] = accA.z; partial[pb + 3] = accA.w;
        partial[pb + 4] = accB.x; partial[pb + 5] = accB.y;
        partial[pb + 6] = accB.z; partial[pb + 7] = accB.w;
    }
    __syncthreads();

    // ---- combine halves + coalesced writeback (1000 contiguous floats) ----
    float* ob = out + (size_t)r * (C_NUM * NCELL) + (size_t)cg * (CHB * NCELL);
    for (int o = tid; o < CHB * NCELL; o += 256) {
        unsigned ch = (unsigned)o / 125u;
        int cell = o - (int)ch * 125;
        float vsum = partial[(cell * 2) * 9 + ch] + partial[(cell * 2 + 1) * 9 + ch];
        ob[o] = vsum * 0.125f;
    }
}

extern "C" void kernel_launch(void* const* d_in, const int* in_sizes, int n_in,
                              void* d_out, int out_size, void* d_ws, size_t ws_size,
                              hipStream_t stream) {
    const float* x0   = (const float*)d_in[0];
    const float* x1   = (const float*)d_in[1];
    const float* x2   = (const float*)d_in[2];
    const float* x3   = (const float*)d_in[3];
    const float* bbox = (const float*)d_in[4];
    const int*   bids = (const int*)d_in[5];
    float* out = (float*)d_out;

    // 128 rois * 8 channel-groups = 1024 blocks
    hipLaunchKernelGGL(pooler_kernel, dim3(1024), dim3(256), 0, stream,
                       x0, x1, x2, x3, bbox, bids, out);
}

// Round 4
// 222.145 us; speedup vs baseline: 1.0025x; 1.0025x over previous
//
#include <hip/hip_runtime.h>
#include <math.h>

#define CHB 8
#define C_NUM 64
#define NCELL 125
#define MAX_VOX 256     // analysis bound: region <= 8*8*4 voxels
#define NITEMS 250      // 125 cells x 2 sample-halves

// XOR bank swizzle on float4 slot index (bijective: XOR low bits with higher bits).
// Bank group of slot P is P mod 8; without swizzle it is (2v+h) mod 8 -> y-steps
// (v stride RZ=4) collide systematically. Swizzle hashes bits 3..5 of L into 0..2.
__device__ __forceinline__ int swz(int L) { return L ^ ((L >> 3) & 7); }

__device__ __forceinline__ void acc8(const float4* __restrict__ rg4, int v, float w,
                                     float4& A, float4& B) {
    int P = swz(v * 2);
    float4 lo = rg4[P];       // channels 0-3 of voxel v
    float4 hi = rg4[P ^ 1];   // channels 4-7 (L=2v+1 -> P^1 since only bit0 differs)
    A.x = fmaf(lo.x, w, A.x); A.y = fmaf(lo.y, w, A.y);
    A.z = fmaf(lo.z, w, A.z); A.w = fmaf(lo.w, w, A.w);
    B.x = fmaf(hi.x, w, B.x); B.y = fmaf(hi.y, w, B.y);
    B.z = fmaf(hi.z, w, B.z); B.w = fmaf(hi.w, w, B.w);
}

// LDS: reg 256*8*4 = 8 KB, partial 250*9*4 = 9 KB
__global__ __launch_bounds__(256, 4) void pooler_kernel(
    const float* __restrict__ x0, const float* __restrict__ x1,
    const float* __restrict__ x2, const float* __restrict__ x3,
    const float* __restrict__ bbox, const int* __restrict__ bids,
    float* __restrict__ out)
{
    __shared__ float reg[MAX_VOX * CHB];   // float4 slot P = swz(2v+h), component = ch&3
    __shared__ float partial[NITEMS * 9];  // [item][ch], padded stride 9

    const int blk = blockIdx.x;
    const int r   = blk >> 3;   // roi (128)
    const int cg  = blk & 7;    // channel group (8 x 8ch)
    const int tid = threadIdx.x;

    // ---- per-roi params (wave-uniform) ----
    const float b0 = bbox[r*7+0], b1 = bbox[r*7+1], b2 = bbox[r*7+2];
    const float b3 = bbox[r*7+3], b4 = bbox[r*7+4], b5 = bbox[r*7+5];
    const float b6 = bbox[r*7+6];
    const int bid  = bids[r];

    // level select: argmin |SC - sqrt(max(b3,b4))/20|, first-min wins
    const float rate = sqrtf(fmaxf(b3, b4)) / 20.0f;
    const float SC[4] = {0.25f, 0.125f, 0.0625f, 0.03125f};
    int lvl = 0;
    float best = fabsf(SC[0] - rate);
    #pragma unroll
    for (int j = 1; j < 4; ++j) {
        float d = fabsf(SC[j] - rate);
        if (d < best) { best = d; lvl = j; }
    }
    const float scale = SC[lvl];

    const float* f; int D;
    if (lvl == 0)      { f = x0; D = 64; }
    else if (lvl == 1) { f = x1; D = 32; }
    else if (lvl == 2) { f = x2; D = 16; }
    else               { f = x3; D = 8;  }
    const float Df = (float)D;

    // roi7 = [b1,b0,b2,b4,b3,b5, b6*(180/pi)]; theta = roi7[6]*(pi/180)
    const float ctr0 = b1 * scale;
    const float ctr1 = b0 * scale;
    const float ctr2 = b2 * scale;
    const float sz0  = b4 * scale;
    const float sz1  = b3 * scale;
    const float sz2  = b5 * scale;
    const float theta = (b6 * (180.0f / (float)M_PI)) * ((float)M_PI / 180.0f);
    float st, ct;
    sincosf(theta, &st, &ct);

    // tight sample-extent bounds: u in [0.05,0.95] -> g in +-0.45*sz
    const float hx = 0.451f * (fabsf(ct) * sz0 + fabsf(st) * sz1) + 0.01f;
    const float hy = 0.451f * (fabsf(st) * sz0 + fabsf(ct) * sz1) + 0.01f;
    const float hz = 0.451f * sz2 + 0.01f;
    const int x_lo = (int)fminf(fmaxf(ctr0 - hx, 0.0f), Df - 1.0f);
    const int y_lo = (int)fminf(fmaxf(ctr1 - hy, 0.0f), Df - 1.0f);
    const int z_lo = (int)fminf(fmaxf(ctr2 - hz, 0.0f), Df - 1.0f);
    const int x_hi = (int)fminf(fmaxf(ctr0 + hx, 0.0f), Df - 1.0f);
    const int y_hi = (int)fminf(fmaxf(ctr1 + hy, 0.0f), Df - 1.0f);
    const int z_hi = (int)fminf(fmaxf(ctr2 + hz, 0.0f), Df - 1.0f);

    const int nx = min(x_hi - x_lo + 2, D - x_lo);   // <= 8 (lvl-select bound)
    const int ny = min(y_hi - y_lo + 2, D - y_lo);   // <= 8
    const int nz = min(z_hi - z_lo + 2, D - z_lo);   // <= 4

    int RX2 = 2; while (RX2 < nx) RX2 <<= 1; RX2 = min(RX2, 8);
    int RY2 = 2; while (RY2 < ny) RY2 <<= 1; RY2 = min(RY2, 8);
    int RZ2 = 2; while (RZ2 < nz) RZ2 <<= 1; RZ2 = min(RZ2, 4);
    const int lz  = __builtin_ctz(RZ2);
    const int ly  = __builtin_ctz(RY2);
    const int lx  = __builtin_ctz(RX2);
    const int sxs = lz + ly;            // x-stride shift
    const int lnv = lx + ly + lz;       // log2(nvox)
    const int nvox = 1 << lnv;

    // ---- phase A: stage region for 8 channels into swizzled LDS ----
    const size_t vox = (size_t)D * D * D;
    const float* fbase = f + ((size_t)bid * C_NUM + (size_t)cg * CHB) * vox;
    const int total_e = nvox * CHB;
    for (int e = tid; e < total_e; e += 256) {
        int ch = e >> lnv;
        int v  = e & (nvox - 1);
        int rz = v & (RZ2 - 1);
        int ry = (v >> lz) & (RY2 - 1);
        int rx = v >> sxs;
        int gx = min(x_lo + rx, D - 1);
        int gy = min(y_lo + ry, D - 1);
        int gz = min(z_lo + rz, D - 1);
        float val = fbase[(size_t)ch * vox + (size_t)(gx * D + gy) * D + gz];
        int P = swz(v * 2 + (ch >> 2));
        reg[P * 4 + (ch & 3)] = val;
    }
    __syncthreads();

    // ---- phase C: one thread = one (cell, sample-half) for all 8 channels ----
    if (tid < NITEMS) {
        const int cell  = tid >> 1;
        const int shalf = tid & 1;
        const int i0 = cell / 25;
        const int rem = cell - i0 * 25;
        const int i1 = rem / 5;
        const int i2 = rem - i1 * 5;

        float4 accA = make_float4(0.f, 0.f, 0.f, 0.f);
        float4 accB = make_float4(0.f, 0.f, 0.f, 0.f);
        const float4* rg4 = (const float4*)reg;

        #pragma unroll
        for (int s = 0; s < 4; ++s) {
            const int s0 = shalf, s1 = (s >> 1) & 1, s2 = s & 1;
            float u0 = ((float)i0 + ((float)s0 + 0.5f) * 0.5f) / 5.0f;
            float u1 = ((float)i1 + ((float)s1 + 0.5f) * 0.5f) / 5.0f;
            float u2 = ((float)i2 + ((float)s2 + 0.5f) * 0.5f) / 5.0f;
            float g0 = (u0 - 0.5f) * sz0;
            float g1 = (u1 - 0.5f) * sz1;
            float g2 = (u2 - 0.5f) * sz2;
            float px = ctr0 + (ct * g0 - st * g1);
            float py = ctr1 + (st * g0 + ct * g1);
            float pz = ctr2 + g2;
            float validf = ((px > -1.0f) && (px < Df) &&
                            (py > -1.0f) && (py < Df) &&
                            (pz > -1.0f) && (pz < Df)) ? 1.0f : 0.0f;
            float q0 = fminf(fmaxf(px, 0.0f), Df - 1.0f);
            float q1 = fminf(fmaxf(py, 0.0f), Df - 1.0f);
            float q2 = fminf(fmaxf(pz, 0.0f), Df - 1.0f);
            int A0 = (int)q0, A1 = (int)q1, A2 = (int)q2;
            float f0 = q0 - (float)A0;
            float f1 = q1 - (float)A1;
            float f2 = q2 - (float)A2;
            int d0 = ((A0 + 1 < D) ? 1 : 0) << sxs;
            int d1 = ((A1 + 1 < D) ? 1 : 0) << lz;
            int d2 = (A2 + 1 < D) ? 1 : 0;
            int base = ((A0 - x_lo) << sxs) + ((A1 - y_lo) << lz) + (A2 - z_lo);

            float wx0 = 1.0f - f0, wx1 = f0;
            float wy0 = 1.0f - f1, wy1 = f1;
            float wz0 = (1.0f - f2) * validf, wz1 = f2 * validf;
            float w00 = wx0 * wy0, w01 = wx0 * wy1;
            float w10 = wx1 * wy0, w11 = wx1 * wy1;

            acc8(rg4, base,                w00 * wz0, accA, accB);
            acc8(rg4, base + d2,           w00 * wz1, accA, accB);
            acc8(rg4, base + d1,           w01 * wz0, accA, accB);
            acc8(rg4, base + d1 + d2,      w01 * wz1, accA, accB);
            acc8(rg4, base + d0,           w10 * wz0, accA, accB);
            acc8(rg4, base + d0 + d2,      w10 * wz1, accA, accB);
            acc8(rg4, base + d0 + d1,      w11 * wz0, accA, accB);
            acc8(rg4, base + d0 + d1 + d2, w11 * wz1, accA, accB);
        }

        const int pb = tid * 9;
        partial[pb + 0] = accA.x; partial[pb + 1] = accA.y;
        partial[pb + 2] = accA.z; partial[pb + 3] = accA.w;
        partial[pb + 4] = accB.x; partial[pb + 5] = accB.y;
        partial[pb + 6] = accB.z; partial[pb + 7] = accB.w;
    }
    __syncthreads();

    // ---- combine halves + vectorized coalesced writeback (250 float4s) ----
    float4* ob4 = (float4*)(out + (size_t)r * (C_NUM * NCELL) + (size_t)cg * (CHB * NCELL));
    for (int q = tid; q < 250; q += 256) {
        float vres[4];
        #pragma unroll
        for (int j = 0; j < 4; ++j) {
            int o = q * 4 + j;              // o = ch*125 + cell
            unsigned ch = (unsigned)o / 125u;
            int cell = o - (int)ch * 125;
            vres[j] = (partial[(cell * 2) * 9 + ch] +
                       partial[(cell * 2 + 1) * 9 + ch]) * 0.125f;
        }
        ob4[q] = make_float4(vres[0], vres[1], vres[2], vres[3]);
    }
}

extern "C" void kernel_launch(void* const* d_in, const int* in_sizes, int n_in,
                              void* d_out, int out_size, void* d_ws, size_t ws_size,
                              hipStream_t stream) {
    const float* x0   = (const float*)d_in[0];
    const float* x1   = (const float*)d_in[1];
    const float* x2   = (const float*)d_in[2];
    const float* x3   = (const float*)d_in[3];
    const float* bbox = (const float*)d_in[4];
    const int*   bids = (const int*)d_in[5];
    float* out = (float*)d_out;

    // 128 rois * 8 channel-groups = 1024 blocks
    hipLaunchKernelGGL(pooler_kernel, dim3(1024), dim3(256), 0, stream,
                       x0, x1, x2, x3, bbox, bids, out);
}

// Round 5
// 188.192 us; speedup vs baseline: 1.1834x; 1.1804x over previous
//
#include <hip/hip_runtime.h>
#include <math.h>

#define CHB 8
#define C_NUM 64
#define NCELL 125
#define MAX_VOX 256     // analysis bound: region <= 8*8*4 voxels
#define NITEMS 250      // 125 cells x 2 sample-halves

// XOR bank swizzle on float4 slot index (bijective: XOR low bits with higher bits).
__device__ __forceinline__ int swz(int L) { return L ^ ((L >> 3) & 7); }

__device__ __forceinline__ void acc8(const float4* __restrict__ rg4, int v, float w,
                                     float4& A, float4& B) {
    int P = swz(v * 2);
    float4 lo = rg4[P];       // channels 0-3 of voxel v
    float4 hi = rg4[P ^ 1];   // channels 4-7
    A.x = fmaf(lo.x, w, A.x); A.y = fmaf(lo.y, w, A.y);
    A.z = fmaf(lo.z, w, A.z); A.w = fmaf(lo.w, w, A.w);
    B.x = fmaf(hi.x, w, B.x); B.y = fmaf(hi.y, w, B.y);
    B.z = fmaf(hi.z, w, B.z); B.w = fmaf(hi.w, w, B.w);
}

// LDS: reg 256*8*4 = 8 KB, partial 250*9*4 = 9 KB
// NOTE: no min-waves clamp — R4's (256,4) capped VGPR at 128 and (theory) forced
// scratch spills in the unrolled phase C. Let the allocator use what it needs.
__global__ __launch_bounds__(256) void pooler_kernel(
    const float* __restrict__ x0, const float* __restrict__ x1,
    const float* __restrict__ x2, const float* __restrict__ x3,
    const float* __restrict__ bbox, const int* __restrict__ bids,
    float* __restrict__ out)
{
    __shared__ float reg[MAX_VOX * CHB];   // float4 slot P = swz(2v+h), component = ch&3
    __shared__ float partial[NITEMS * 9];  // [item][ch], padded stride 9

    const int blk = blockIdx.x;
    const int r   = blk >> 3;   // roi (128)
    const int cg  = blk & 7;    // channel group (8 x 8ch)
    const int tid = threadIdx.x;

    // ---- per-roi params (wave-uniform) ----
    const float b0 = bbox[r*7+0], b1 = bbox[r*7+1], b2 = bbox[r*7+2];
    const float b3 = bbox[r*7+3], b4 = bbox[r*7+4], b5 = bbox[r*7+5];
    const float b6 = bbox[r*7+6];
    const int bid  = bids[r];

    // level select: argmin |SC - sqrt(max(b3,b4))/20|, first-min wins
    const float rate = sqrtf(fmaxf(b3, b4)) / 20.0f;
    const float SC[4] = {0.25f, 0.125f, 0.0625f, 0.03125f};
    int lvl = 0;
    float best = fabsf(SC[0] - rate);
    #pragma unroll
    for (int j = 1; j < 4; ++j) {
        float d = fabsf(SC[j] - rate);
        if (d < best) { best = d; lvl = j; }
    }
    const float scale = SC[lvl];

    const float* f; int D;
    if (lvl == 0)      { f = x0; D = 64; }
    else if (lvl == 1) { f = x1; D = 32; }
    else if (lvl == 2) { f = x2; D = 16; }
    else               { f = x3; D = 8;  }
    const float Df = (float)D;

    // roi7 = [b1,b0,b2,b4,b3,b5, b6*(180/pi)]; theta = roi7[6]*(pi/180)
    const float ctr0 = b1 * scale;
    const float ctr1 = b0 * scale;
    const float ctr2 = b2 * scale;
    const float sz0  = b4 * scale;
    const float sz1  = b3 * scale;
    const float sz2  = b5 * scale;
    const float theta = (b6 * (180.0f / (float)M_PI)) * ((float)M_PI / 180.0f);
    float st, ct;
    sincosf(theta, &st, &ct);

    // tight sample-extent bounds: u in [0.05,0.95] -> g in +-0.45*sz
    const float hx = 0.451f * (fabsf(ct) * sz0 + fabsf(st) * sz1) + 0.01f;
    const float hy = 0.451f * (fabsf(st) * sz0 + fabsf(ct) * sz1) + 0.01f;
    const float hz = 0.451f * sz2 + 0.01f;
    const int x_lo = (int)fminf(fmaxf(ctr0 - hx, 0.0f), Df - 1.0f);
    const int y_lo = (int)fminf(fmaxf(ctr1 - hy, 0.0f), Df - 1.0f);
    const int z_lo = (int)fminf(fmaxf(ctr2 - hz, 0.0f), Df - 1.0f);
    const int x_hi = (int)fminf(fmaxf(ctr0 + hx, 0.0f), Df - 1.0f);
    const int y_hi = (int)fminf(fmaxf(ctr1 + hy, 0.0f), Df - 1.0f);
    const int z_hi = (int)fminf(fmaxf(ctr2 + hz, 0.0f), Df - 1.0f);

    const int nx = min(x_hi - x_lo + 2, D - x_lo);   // <= 8 (lvl-select bound)
    const int ny = min(y_hi - y_lo + 2, D - y_lo);   // <= 8
    const int nz = min(z_hi - z_lo + 2, D - z_lo);   // <= 4

    int RX2 = 2; while (RX2 < nx) RX2 <<= 1; RX2 = min(RX2, 8);
    int RY2 = 2; while (RY2 < ny) RY2 <<= 1; RY2 = min(RY2, 8);
    int RZ2 = 2; while (RZ2 < nz) RZ2 <<= 1; RZ2 = min(RZ2, 4);
    const int lz  = __builtin_ctz(RZ2);
    const int ly  = __builtin_ctz(RY2);
    const int lx  = __builtin_ctz(RX2);
    const int sxs = lz + ly;            // x-stride shift
    const int lnv = lx + ly + lz;       // log2(nvox)
    const int nvox = 1 << lnv;

    // ---- phase A: stage region for 8 channels into swizzled LDS ----
    const size_t vox = (size_t)D * D * D;
    const float* fbase = f + ((size_t)bid * C_NUM + (size_t)cg * CHB) * vox;
    const int total_e = nvox * CHB;
    for (int e = tid; e < total_e; e += 256) {
        int ch = e >> lnv;
        int v  = e & (nvox - 1);
        int rz = v & (RZ2 - 1);
        int ry = (v >> lz) & (RY2 - 1);
        int rx = v >> sxs;
        int gx = min(x_lo + rx, D - 1);
        int gy = min(y_lo + ry, D - 1);
        int gz = min(z_lo + rz, D - 1);
        float val = fbase[(size_t)ch * vox + (size_t)(gx * D + gy) * D + gz];
        int P = swz(v * 2 + (ch >> 2));
        reg[P * 4 + (ch & 3)] = val;
    }
    __syncthreads();

    // ---- phase C: one thread = one (cell, sample-half) for all 8 channels ----
    if (tid < NITEMS) {
        const int cell  = tid >> 1;
        const int shalf = tid & 1;
        const int i0 = cell / 25;
        const int rem = cell - i0 * 25;
        const int i1 = rem / 5;
        const int i2 = rem - i1 * 5;

        float4 accA = make_float4(0.f, 0.f, 0.f, 0.f);
        float4 accB = make_float4(0.f, 0.f, 0.f, 0.f);
        const float4* rg4 = (const float4*)reg;

        #pragma unroll
        for (int s = 0; s < 4; ++s) {
            const int s0 = shalf, s1 = (s >> 1) & 1, s2 = s & 1;
            float u0 = ((float)i0 + ((float)s0 + 0.5f) * 0.5f) / 5.0f;
            float u1 = ((float)i1 + ((float)s1 + 0.5f) * 0.5f) / 5.0f;
            float u2 = ((float)i2 + ((float)s2 + 0.5f) * 0.5f) / 5.0f;
            float g0 = (u0 - 0.5f) * sz0;
            float g1 = (u1 - 0.5f) * sz1;
            float g2 = (u2 - 0.5f) * sz2;
            float px = ctr0 + (ct * g0 - st * g1);
            float py = ctr1 + (st * g0 + ct * g1);
            float pz = ctr2 + g2;
            float validf = ((px > -1.0f) && (px < Df) &&
                            (py > -1.0f) && (py < Df) &&
                            (pz > -1.0f) && (pz < Df)) ? 1.0f : 0.0f;
            float q0 = fminf(fmaxf(px, 0.0f), Df - 1.0f);
            float q1 = fminf(fmaxf(py, 0.0f), Df - 1.0f);
            float q2 = fminf(fmaxf(pz, 0.0f), Df - 1.0f);
            int A0 = (int)q0, A1 = (int)q1, A2 = (int)q2;
            float f0 = q0 - (float)A0;
            float f1 = q1 - (float)A1;
            float f2 = q2 - (float)A2;
            int d0 = ((A0 + 1 < D) ? 1 : 0) << sxs;
            int d1 = ((A1 + 1 < D) ? 1 : 0) << lz;
            int d2 = (A2 + 1 < D) ? 1 : 0;
            int base = ((A0 - x_lo) << sxs) + ((A1 - y_lo) << lz) + (A2 - z_lo);

            float wx0 = 1.0f - f0, wx1 = f0;
            float wy0 = 1.0f - f1, wy1 = f1;
            float wz0 = (1.0f - f2) * validf, wz1 = f2 * validf;
            float w00 = wx0 * wy0, w01 = wx0 * wy1;
            float w10 = wx1 * wy0, w11 = wx1 * wy1;

            acc8(rg4, base,                w00 * wz0, accA, accB);
            acc8(rg4, base + d2,           w00 * wz1, accA, accB);
            acc8(rg4, base + d1,           w01 * wz0, accA, accB);
            acc8(rg4, base + d1 + d2,      w01 * wz1, accA, accB);
            acc8(rg4, base + d0,           w10 * wz0, accA, accB);
            acc8(rg4, base + d0 + d2,      w10 * wz1, accA, accB);
            acc8(rg4, base + d0 + d1,      w11 * wz0, accA, accB);
            acc8(rg4, base + d0 + d1 + d2, w11 * wz1, accA, accB);
        }

        const int pb = tid * 9;
        partial[pb + 0] = accA.x; partial[pb + 1] = accA.y;
        partial[pb + 2] = accA.z; partial[pb + 3] = accA.w;
        partial[pb + 4] = accB.x; partial[pb + 5] = accB.y;
        partial[pb + 6] = accB.z; partial[pb + 7] = accB.w;
    }
    __syncthreads();

    // ---- combine halves + vectorized coalesced writeback (250 float4s) ----
    float4* ob4 = (float4*)(out + (size_t)r * (C_NUM * NCELL) + (size_t)cg * (CHB * NCELL));
    for (int q = tid; q < 250; q += 256) {
        float vres[4];
        #pragma unroll
        for (int j = 0; j < 4; ++j) {
            int o = q * 4 + j;              // o = ch*125 + cell
            unsigned ch = (unsigned)o / 125u;
            int cell = o - (int)ch * 125;
            vres[j] = (partial[(cell * 2) * 9 + ch] +
                       partial[(cell * 2 + 1) * 9 + ch]) * 0.125f;
        }
        ob4[q] = make_float4(vres[0], vres[1], vres[2], vres[3]);
    }
}

extern "C" void kernel_launch(void* const* d_in, const int* in_sizes, int n_in,
                              void* d_out, int out_size, void* d_ws, size_t ws_size,
                              hipStream_t stream) {
    const float* x0   = (const float*)d_in[0];
    const float* x1   = (const float*)d_in[1];
    const float* x2   = (const float*)d_in[2];
    const float* x3   = (const float*)d_in[3];
    const float* bbox = (const float*)d_in[4];
    const int*   bids = (const int*)d_in[5];
    float* out = (float*)d_out;

    // 128 rois * 8 channel-groups = 1024 blocks
    hipLaunchKernelGGL(pooler_kernel, dim3(1024), dim3(256), 0, stream,
                       x0, x1, x2, x3, bbox, bids, out);
}